// Round 3
// baseline (154.166 us; speedup 1.0000x reference)
//
#include <hip/hip_runtime.h>
#include <math.h>

// Problem constants: N=128, LQ=LK=64, D=512, H=8 (head split is a no-op in the einsum).
#define DN 512          // feature dim
#define NB 128          // batch N

typedef unsigned short ushort_t;
typedef __attribute__((ext_vector_type(8))) short bf16x8;
typedef __attribute__((ext_vector_type(4))) float f32x4;

static __device__ __forceinline__ ushort_t f2bf(float f){
  unsigned u = __float_as_uint(f);
  u += 0x7fffu + ((u >> 16) & 1u);   // round-to-nearest-even
  return (ushort_t)(u >> 16);
}

// async global->LDS, 16B per lane; LDS dest is wave-uniform base + lane*16
#define GLL16(gp, lp)                                                          \
  __builtin_amdgcn_global_load_lds(                                            \
      (const __attribute__((address_space(1))) void*)(gp),                     \
      (__attribute__((address_space(3))) void*)(lp), 16, 0, 0)

#define BAR() __builtin_amdgcn_s_barrier()
#define LGKM0()                                                                \
  do {                                                                         \
    asm volatile("s_waitcnt lgkmcnt(0)" ::: "memory");                         \
    __builtin_amdgcn_sched_barrier(0);                                         \
  } while (0)
#define VMC(N)                                                                 \
  do {                                                                         \
    asm volatile("s_waitcnt vmcnt(" #N ")" ::: "memory");                      \
  } while (0)

// ---------------------------------------------------------------------------
// Projections (both Q and K in one launch; z selects). Out = X @ W^T + bias,
// 128x128 tile, BK=64, 4 waves. LDS uses 16B-slot XOR swizzle (slot ^= row&7).
__global__ __launch_bounds__(256) void proj_kernel(const float* __restrict__ Xq,
                                                   const float* __restrict__ Wq,
                                                   const float* __restrict__ bq,
                                                   ushort_t* __restrict__ Oq,
                                                   const float* __restrict__ Xk,
                                                   const float* __restrict__ Wk,
                                                   const float* __restrict__ bk,
                                                   ushort_t* __restrict__ Ok) {
  const float* X = blockIdx.z ? Xk : Xq;
  const float* W = blockIdx.z ? Wk : Wq;
  const float* bias = blockIdx.z ? bk : bq;
  ushort_t* Out = blockIdx.z ? Ok : Oq;

  __shared__ __align__(16) ushort_t As[128 * 64];
  __shared__ __align__(16) ushort_t Bs[128 * 64];
  const int tid = threadIdx.x;
  const int wave = tid >> 6, lane = tid & 63;
  const int wr = wave >> 1, wc = wave & 1;
  const int m0 = blockIdx.y * 128, n0 = blockIdx.x * 128;
  const int arow = lane & 15, g = lane >> 4;

  f32x4 acc[4][4] = {};

  for (int kt = 0; kt < 8; ++kt) {
    const int k0 = kt * 64;
#pragma unroll
    for (int i = 0; i < 8; i++) {
      int e = i * 1024 + tid * 4;
      int r = e >> 6, c = e & 63;
      int cs = ((((c >> 3) ^ (r & 7)) << 3) | (c & 7));
      float4 va = *(const float4*)&X[(size_t)(m0 + r) * DN + k0 + c];
      ushort4 ha;
      ha.x = f2bf(va.x); ha.y = f2bf(va.y); ha.z = f2bf(va.z); ha.w = f2bf(va.w);
      *(ushort4*)&As[r * 64 + cs] = ha;
      float4 vb = *(const float4*)&W[(size_t)(n0 + r) * DN + k0 + c];
      ushort4 hb;
      hb.x = f2bf(vb.x); hb.y = f2bf(vb.y); hb.z = f2bf(vb.z); hb.w = f2bf(vb.w);
      *(ushort4*)&Bs[r * 64 + cs] = hb;
    }
    __syncthreads();

    bf16x8 af[4][2], bfr[4][2];
#pragma unroll
    for (int mi = 0; mi < 4; mi++)
#pragma unroll
      for (int ks = 0; ks < 2; ks++)
        af[mi][ks] = *(const bf16x8*)&As[(wr * 64 + mi * 16 + arow) * 64 +
                                         ((((ks << 2) | g) ^ (arow & 7)) << 3)];
#pragma unroll
    for (int ni = 0; ni < 4; ni++)
#pragma unroll
      for (int ks = 0; ks < 2; ks++)
        bfr[ni][ks] = *(const bf16x8*)&Bs[(wc * 64 + ni * 16 + arow) * 64 +
                                          ((((ks << 2) | g) ^ (arow & 7)) << 3)];
#pragma unroll
    for (int ks = 0; ks < 2; ks++)
#pragma unroll
      for (int mi = 0; mi < 4; mi++)
#pragma unroll
        for (int ni = 0; ni < 4; ni++)
          acc[mi][ni] = __builtin_amdgcn_mfma_f32_16x16x32_bf16(
              af[mi][ks], bfr[ni][ks], acc[mi][ni], 0, 0, 0);
    __syncthreads();
  }

  float bc[4];
#pragma unroll
  for (int ni = 0; ni < 4; ni++) bc[ni] = bias[n0 + wc * 64 + ni * 16 + arow];
#pragma unroll
  for (int mi = 0; mi < 4; mi++)
#pragma unroll
    for (int ni = 0; ni < 4; ni++)
#pragma unroll
      for (int j = 0; j < 4; j++) {
        int row = m0 + wr * 64 + mi * 16 + (lane >> 4) * 4 + j;
        int col = n0 + wc * 64 + ni * 16 + arow;
        Out[(size_t)row * DN + col] = f2bf(acc[mi][ni][j] + bc[ni]);
      }
}

// ---------------------------------------------------------------------------
// Pairwise logits + fused max/sum reductions.
// 256 blocks (1/CU). Block (by, bxg): a-rows by*256..+256, sweeps 4 b-tiles
// bxt = bxg*4+bxi (cols bxt*256..+256) as one continuous 32-K-tile pipeline.
// 8 waves (2M x 4N), per-wave output 128x64. Phases per K-tile: (mhalf, khalf),
// B frags register-reused across m-halves. Stage units per tile: B-lo, B-hi,
// A-u0 (rows 0-63,128-191), A-u1 (rows 64-127,192-255); ph0 needs {B-lo,B-hi,
// A-u0}, ph1 needs {A-u1} -> vmcnt(2) after ph0-MMA and after ph3-MMA.
__global__ __launch_bounds__(512, 2) void pairs_kernel(const ushort_t* __restrict__ Q,
                                                       const ushort_t* __restrict__ Km,
                                                       const float* __restrict__ amask,
                                                       const float* __restrict__ ls_ptr,
                                                       float* __restrict__ out) {
  __shared__ __align__(16) ushort_t lds[2 * 2 * 256 * 64];  // 128 KiB
  const int tid = threadIdx.x;
  const int wave = tid >> 6, lane = tid & 63;
  const int wr = wave >> 2, wc = wave & 3;
  const int arow = lane & 15, g = lane >> 4;
  const int bid = blockIdx.x;
  const int by = bid >> 3, bxg = bid & 7;
  const int l8 = lane >> 3, l7 = lane & 7;
  const int srcSlot = l7 ^ l8;

  // epilogue scalars first (their vmem drains before staging starts)
  const float lsv = expf(ls_ptr[0]);
  float am2[2];
#pragma unroll
  for (int ph = 0; ph < 2; ph++) {
    float am = amask[(by * 4 + wr * 2 + ph) * 64 + lane];
#pragma unroll
    for (int off = 1; off < 64; off <<= 1) am += __shfl_xor(am, off);
    am2[ph] = am;
  }

  f32x4 acc[8][4];
#pragma unroll
  for (int i = 0; i < 8; i++)
#pragma unroll
    for (int j = 0; j < 4; j++) acc[i][j] = f32x4{0.f, 0.f, 0.f, 0.f};
  bf16x8 aR[4], bR[4];

  // stage A unit u (u0: rows 0-63 & 128-191; u1: rows 64-127 & 192-255)
  auto SA = [&](int u, int k, int d) {
    int base = (wave >> 2) * 128 + u * 64 + (wave & 3) * 16;
#pragma unroll
    for (int i = 0; i < 2; i++) {
      int row = base + i * 8;
      GLL16(Q + (size_t)(by * 256 + row + l8) * DN + k * 64 + srcSlot * 8,
            &lds[((d * 2 + 0) * 256 + row) * 64]);
    }
  };
  auto SB = [&](int half, int k, int bxt, int d) {
#pragma unroll
    for (int i = 0; i < 2; i++) {
      int row = half * 128 + wave * 16 + i * 8;
      GLL16(Km + (size_t)(bxt * 256 + row + l8) * DN + k * 64 + srcSlot * 8,
            &lds[((d * 2 + 1) * 256 + row) * 64]);
    }
  };
  auto LDA = [&](int mh, int ks, int d) {
#pragma unroll
    for (int mi = 0; mi < 4; mi++) {
      int row = wr * 128 + (mh * 4 + mi) * 16 + arow;
      int slot = ((ks << 2) | g) ^ (arow & 7);
      aR[mi] = *(const bf16x8*)&lds[((d * 2 + 0) * 256 + row) * 64 + slot * 8];
    }
  };
  auto LDB = [&](int ks, int d) {
#pragma unroll
    for (int ni = 0; ni < 4; ni++) {
      int row = wc * 64 + ni * 16 + arow;
      int slot = ((ks << 2) | g) ^ (arow & 7);
      bR[ni] = *(const bf16x8*)&lds[((d * 2 + 1) * 256 + row) * 64 + slot * 8];
    }
  };
  auto MMA = [&](int mh) {
    __builtin_amdgcn_s_setprio(1);
#pragma unroll
    for (int mi = 0; mi < 4; mi++)
#pragma unroll
      for (int ni = 0; ni < 4; ni++)
        acc[mh * 4 + mi][ni] = __builtin_amdgcn_mfma_f32_16x16x32_bf16(
            aR[mi], bR[ni], acc[mh * 4 + mi][ni], 0, 0, 0);
    __builtin_amdgcn_s_setprio(0);
  };

  // prologue: stage tile 0 (B-lo, B-hi, A-u0, A-u1), leave A-u1 in flight
  {
    const int bxt0 = bxg * 4;
    SB(0, 0, bxt0, 0);
    SB(1, 0, bxt0, 0);
    SA(0, 0, 0);
    SA(1, 0, 0);
    VMC(2);
    BAR();
  }

#pragma unroll 1
  for (int bxi = 0; bxi < 4; ++bxi) {
    const int bxt = bxg * 4 + bxi;
#pragma unroll
    for (int k = 0; k < 8; ++k) {
      const int d = k & 1, dn = d ^ 1;
      const int kn = (k + 1) & 7;
      const int sbxt = (k == 7) ? bxt + 1 : bxt;          // source tile for T+1
      const bool doST = !(k == 7 && bxi == 3);            // skip past last tile
      // ph0: mh=0, ks=0
      LDA(0, 0, d); LDB(0, d);
      if (doST) SB(0, kn, sbxt, dn);
      BAR(); LGKM0();
      MMA(0);
      if (k == 7) { if (bxi == 3) { VMC(0); } else { VMC(2); } } else { VMC(2); }
      BAR();
      // ph1: mh=1, ks=0 (B regs reused)
      LDA(1, 0, d);
      if (doST) SB(1, kn, sbxt, dn);
      BAR(); LGKM0();
      MMA(1);
      BAR();
      // ph2: mh=0, ks=1
      LDA(0, 1, d); LDB(1, d);
      if (doST) SA(0, kn, dn);
      BAR(); LGKM0();
      MMA(0);
      BAR();
      // ph3: mh=1, ks=1; boundary wait validates next tile's {B-lo,B-hi,A-u0}
      LDA(1, 1, d);
      if (doST) SA(1, kn, dn);
      BAR(); LGKM0();
      MMA(1);
      VMC(2);
      BAR();
    }

    // ---- per-sub-tile epilogue: two (a,b) pairs per wave ----
    // C/D layout: col = lane&15, row = (lane>>4)*4 + reg.
#pragma unroll
    for (int ph = 0; ph < 2; ph++) {
      float t2v = 0.f;
#pragma unroll
      for (int mi = ph * 4; mi < ph * 4 + 4; mi++) {
        f32x4 rm = acc[mi][0];
#pragma unroll
        for (int ni = 1; ni < 4; ni++)
#pragma unroll
          for (int j = 0; j < 4; j++) rm[j] = fmaxf(rm[j], acc[mi][ni][j]);
#pragma unroll
        for (int off = 1; off < 16; off <<= 1)
#pragma unroll
          for (int j = 0; j < 4; j++) rm[j] = fmaxf(rm[j], __shfl_xor(rm[j], off));
        t2v += rm[0] + rm[1] + rm[2] + rm[3];
      }
      t2v += __shfl_xor(t2v, 16);
      t2v += __shfl_xor(t2v, 32);

      float v2t = 0.f;
#pragma unroll
      for (int ni = 0; ni < 4; ni++) {
        float cm = -INFINITY;
#pragma unroll
        for (int mi = ph * 4; mi < ph * 4 + 4; mi++)
#pragma unroll
          for (int j = 0; j < 4; j++) cm = fmaxf(cm, acc[mi][ni][j]);
        cm = fmaxf(cm, __shfl_xor(cm, 16));
        cm = fmaxf(cm, __shfl_xor(cm, 32));
        v2t += cm;
      }
#pragma unroll
      for (int off = 1; off < 16; off <<= 1) v2t += __shfl_xor(v2t, off);

      const int a = by * 4 + wr * 2 + ph, b = bxt * 4 + wc;
      float r = lsv * 0.5f * (t2v / am2[ph] + v2t / 64.0f);
      if (lane == 0) {
        out[a * NB + b] = r;                 // r
        out[NB * NB + b * NB + a] = r;       // r.T
      }
    }
    // reset accumulators for next sub-tile
#pragma unroll
    for (int i = 0; i < 8; i++)
#pragma unroll
      for (int j = 0; j < 4; j++) acc[i][j] = f32x4{0.f, 0.f, 0.f, 0.f};
  }
}

// ---------------------------------------------------------------------------
extern "C" void kernel_launch(void* const* d_in, const int* in_sizes, int n_in,
                              void* d_out, int out_size, void* d_ws, size_t ws_size,
                              hipStream_t stream) {
  const float* query = (const float*)d_in[0];
  const float* key   = (const float*)d_in[1];
  const float* amask = (const float*)d_in[2];
  const float* Wq    = (const float*)d_in[3];
  const float* bq    = (const float*)d_in[4];
  const float* Wk    = (const float*)d_in[5];
  const float* bk    = (const float*)d_in[6];
  const float* ls    = (const float*)d_in[7];

  char* ws = (char*)d_ws;
  ushort_t* Qb = (ushort_t*)(ws);                      // 8 MB
  ushort_t* Kb = (ushort_t*)(ws + 8 * 1024 * 1024);    // 8 MB

  proj_kernel<<<dim3(4, 64, 2), 256, 0, stream>>>(query, Wq, bq, Qb, key, Wk, bk, Kb);
  pairs_kernel<<<dim3(256), 512, 0, stream>>>(Qb, Kb, amask, ls, (float*)d_out);
}

// Round 4
// 98.973 us; speedup vs baseline: 1.5577x; 1.5577x over previous
//
#include <hip/hip_runtime.h>
#include <math.h>

// Problem constants: N=128, LQ=LK=64, D=512, H=8 (head split is a no-op in the einsum).
#define DN 512          // feature dim
#define NB 128          // batch N

typedef unsigned short ushort_t;
typedef __attribute__((ext_vector_type(8))) short bf16x8;
typedef __attribute__((ext_vector_type(4))) float f32x4;

static __device__ __forceinline__ ushort_t f2bf(float f){
  unsigned u = __float_as_uint(f);
  u += 0x7fffu + ((u >> 16) & 1u);   // round-to-nearest-even
  return (ushort_t)(u >> 16);
}

// async global->LDS, 16B per lane; LDS dest is wave-uniform base + lane*16
#define GLL16(gp, lp)                                                          \
  __builtin_amdgcn_global_load_lds(                                            \
      (const __attribute__((address_space(1))) void*)(gp),                     \
      (__attribute__((address_space(3))) void*)(lp), 16, 0, 0)

#define BAR() __builtin_amdgcn_s_barrier()
#define SCHED0() __builtin_amdgcn_sched_barrier(0)
#define VMC(N)                                                                 \
  do {                                                                         \
    asm volatile("s_waitcnt vmcnt(" #N ")" ::: "memory");                      \
  } while (0)

// ---------------------------------------------------------------------------
// Projections (both Q and K in one launch; z selects). Out = X @ W^T + bias,
// 128x128 tile, BK=64, 4 waves. LDS uses 16B-slot XOR swizzle (slot ^= row&7).
__global__ __launch_bounds__(256) void proj_kernel(const float* __restrict__ Xq,
                                                   const float* __restrict__ Wq,
                                                   const float* __restrict__ bq,
                                                   ushort_t* __restrict__ Oq,
                                                   const float* __restrict__ Xk,
                                                   const float* __restrict__ Wk,
                                                   const float* __restrict__ bk,
                                                   ushort_t* __restrict__ Ok) {
  const float* X = blockIdx.z ? Xk : Xq;
  const float* W = blockIdx.z ? Wk : Wq;
  const float* bias = blockIdx.z ? bk : bq;
  ushort_t* Out = blockIdx.z ? Ok : Oq;

  __shared__ __align__(16) ushort_t As[128 * 64];
  __shared__ __align__(16) ushort_t Bs[128 * 64];
  const int tid = threadIdx.x;
  const int wave = tid >> 6, lane = tid & 63;
  const int wr = wave >> 1, wc = wave & 1;
  const int m0 = blockIdx.y * 128, n0 = blockIdx.x * 128;
  const int arow = lane & 15, g = lane >> 4;

  f32x4 acc[4][4] = {};

  for (int kt = 0; kt < 8; ++kt) {
    const int k0 = kt * 64;
#pragma unroll
    for (int i = 0; i < 8; i++) {
      int e = i * 1024 + tid * 4;
      int r = e >> 6, c = e & 63;
      int cs = ((((c >> 3) ^ (r & 7)) << 3) | (c & 7));
      float4 va = *(const float4*)&X[(size_t)(m0 + r) * DN + k0 + c];
      ushort4 ha;
      ha.x = f2bf(va.x); ha.y = f2bf(va.y); ha.z = f2bf(va.z); ha.w = f2bf(va.w);
      *(ushort4*)&As[r * 64 + cs] = ha;
      float4 vb = *(const float4*)&W[(size_t)(n0 + r) * DN + k0 + c];
      ushort4 hb;
      hb.x = f2bf(vb.x); hb.y = f2bf(vb.y); hb.z = f2bf(vb.z); hb.w = f2bf(vb.w);
      *(ushort4*)&Bs[r * 64 + cs] = hb;
    }
    __syncthreads();

    bf16x8 af[4][2], bfr[4][2];
#pragma unroll
    for (int mi = 0; mi < 4; mi++)
#pragma unroll
      for (int ks = 0; ks < 2; ks++)
        af[mi][ks] = *(const bf16x8*)&As[(wr * 64 + mi * 16 + arow) * 64 +
                                         ((((ks << 2) | g) ^ (arow & 7)) << 3)];
#pragma unroll
    for (int ni = 0; ni < 4; ni++)
#pragma unroll
      for (int ks = 0; ks < 2; ks++)
        bfr[ni][ks] = *(const bf16x8*)&Bs[(wc * 64 + ni * 16 + arow) * 64 +
                                          ((((ks << 2) | g) ^ (arow & 7)) << 3)];
#pragma unroll
    for (int ks = 0; ks < 2; ks++)
#pragma unroll
      for (int mi = 0; mi < 4; mi++)
#pragma unroll
        for (int ni = 0; ni < 4; ni++)
          acc[mi][ni] = __builtin_amdgcn_mfma_f32_16x16x32_bf16(
              af[mi][ks], bfr[ni][ks], acc[mi][ni], 0, 0, 0);
    __syncthreads();
  }

  float bc[4];
#pragma unroll
  for (int ni = 0; ni < 4; ni++) bc[ni] = bias[n0 + wc * 64 + ni * 16 + arow];
#pragma unroll
  for (int mi = 0; mi < 4; mi++)
#pragma unroll
    for (int ni = 0; ni < 4; ni++)
#pragma unroll
      for (int j = 0; j < 4; j++) {
        int row = m0 + wr * 64 + mi * 16 + (lane >> 4) * 4 + j;
        int col = n0 + wc * 64 + ni * 16 + arow;
        Out[(size_t)row * DN + col] = f2bf(acc[mi][ni][j] + bc[ni]);
      }
}

// ---------------------------------------------------------------------------
// Pairwise logits + fused max/sum reductions. One 256x256 output tile per
// block (4 a's x 4 b's), 8 waves (2M x 4N), K-loop 8 tiles of BK=64 with
// double-buffered LDS, ONE barrier per K-tile, counted vmcnt (never 0 in the
// steady state). XCD-rectangle block swizzle: each XCD gets a 4x8 (by,bx)
// rectangle per generation -> 3 MB working set < 4 MB XCD L2.
__global__ __launch_bounds__(512, 2) void pairs_kernel(const ushort_t* __restrict__ Q,
                                                       const ushort_t* __restrict__ Km,
                                                       const float* __restrict__ amask,
                                                       const float* __restrict__ ls_ptr,
                                                       float* __restrict__ out) {
  __shared__ __align__(16) ushort_t lds[2 * 2 * 256 * 64];  // 128 KiB
  const int tid = threadIdx.x;
  const int wave = tid >> 6, lane = tid & 63;
  const int wr = wave >> 2, wc = wave & 3;
  const int arow = lane & 15, g = lane >> 4;

  const int bid = blockIdx.x;
  const int gen = bid >> 8, slot = bid & 255;
  const int xcd = slot & 7, idx = slot >> 3;
  const int by = ((gen & 1) << 4) + ((xcd >> 1) << 2) + (idx >> 3);
  const int bx = ((gen >> 1) << 4) + ((xcd & 1) << 3) + (idx & 7);

  const int l8 = lane >> 3, l7 = lane & 7;
  const int srcSlot = l7 ^ l8;

  // epilogue scalars first; force their vmem drained before the pipeline
  const float lsv = expf(ls_ptr[0]);
  float am2[2];
#pragma unroll
  for (int ph = 0; ph < 2; ph++) {
    float am = amask[(by * 4 + wr * 2 + ph) * 64 + lane];
#pragma unroll
    for (int off = 1; off < 64; off <<= 1) am += __shfl_xor(am, off);
    am2[ph] = am;
  }
  VMC(0); SCHED0();   // no stray loads outstanding: vmcnt counts below are exact

  f32x4 acc[8][4] = {};
  bf16x8 aA[4], aB[4], bR0[4], bR1[4];

  // stage A unit u (u0: rows 0-63 & 128-191; u1: rows 64-127 & 192-255)
  auto SA = [&](int u, int k, int d) {
    int base = (wave >> 2) * 128 + u * 64 + (wave & 3) * 16;
#pragma unroll
    for (int i = 0; i < 2; i++) {
      int row = base + i * 8;
      GLL16(Q + (size_t)(by * 256 + row + l8) * DN + k * 64 + srcSlot * 8,
            &lds[((d * 2 + 0) * 256 + row) * 64]);
    }
  };
  auto SB = [&](int half, int k, int d) {
#pragma unroll
    for (int i = 0; i < 2; i++) {
      int row = half * 128 + wave * 16 + i * 8;
      GLL16(Km + (size_t)(bx * 256 + row + l8) * DN + k * 64 + srcSlot * 8,
            &lds[((d * 2 + 1) * 256 + row) * 64]);
    }
  };
  auto LDA = [&](bf16x8* ar, int mh, int ks, int d) {
#pragma unroll
    for (int mi = 0; mi < 4; mi++) {
      int row = wr * 128 + (mh * 4 + mi) * 16 + arow;
      int slt = ((ks << 2) | g) ^ (arow & 7);
      ar[mi] = *(const bf16x8*)&lds[((d * 2 + 0) * 256 + row) * 64 + slt * 8];
    }
  };
  auto LDB = [&](bf16x8* br, int ks, int d) {
#pragma unroll
    for (int ni = 0; ni < 4; ni++) {
      int row = wc * 64 + ni * 16 + arow;
      int slt = ((ks << 2) | g) ^ (arow & 7);
      br[ni] = *(const bf16x8*)&lds[((d * 2 + 1) * 256 + row) * 64 + slt * 8];
    }
  };
  auto MMA = [&](int mh, bf16x8* ar, bf16x8* br) {
    __builtin_amdgcn_s_setprio(1);
#pragma unroll
    for (int mi = 0; mi < 4; mi++)
#pragma unroll
      for (int ni = 0; ni < 4; ni++)
        acc[mh * 4 + mi][ni] = __builtin_amdgcn_mfma_f32_16x16x32_bf16(
            ar[mi], br[ni], acc[mh * 4 + mi][ni], 0, 0, 0);
    __builtin_amdgcn_s_setprio(0);
  };

  // prologue: stage tile 0 fully; wait {B-lo,B-hi,A-u0}, leave A-u1 in flight
  SB(0, 0, 0); SB(1, 0, 0); SA(0, 0, 0); SA(1, 0, 0);
  VMC(2);
  BAR(); SCHED0();

#pragma unroll
  for (int k = 0; k < 8; ++k) {
    const int d = k & 1, dn = d ^ 1;
    const bool doST = (k < 7);
    // issue next tile's 8 stage loads first (issue-early, land-late)
    if (doST) { SB(0, k + 1, dn); SB(1, k + 1, dn); SA(0, k + 1, dn); SA(1, k + 1, dn); }
    // mh=0 halves (rows in A-u0; B validated at boundary)
    LDB(bR0, 0, d); LDB(bR1, 1, d);
    LDA(aA, 0, 0, d); MMA(0, aA, bR0);
    LDA(aB, 0, 1, d); MMA(0, aB, bR1);
    // A-u1 of THIS tile was left in flight: validate (waits 2 oldest)
    if (doST) { VMC(8); } else { VMC(0); }
    LDA(aA, 1, 0, d); MMA(1, aA, bR0);
    LDA(aB, 1, 1, d); MMA(1, aB, bR1);
    // boundary: next tile's {B-lo,B-hi,A-u0} done, leave its A-u1 in flight
    if (doST) { VMC(2); }
    BAR(); SCHED0();
  }

  // ---- fused epilogue: two (a,b) pairs per wave ----
  // C/D layout: col = lane&15, row = (lane>>4)*4 + reg.
#pragma unroll
  for (int ph = 0; ph < 2; ph++) {
    float t2v = 0.f;
#pragma unroll
    for (int mi = ph * 4; mi < ph * 4 + 4; mi++) {
      f32x4 rm = acc[mi][0];
#pragma unroll
      for (int ni = 1; ni < 4; ni++)
#pragma unroll
        for (int j = 0; j < 4; j++) rm[j] = fmaxf(rm[j], acc[mi][ni][j]);
#pragma unroll
      for (int off = 1; off < 16; off <<= 1)
#pragma unroll
        for (int j = 0; j < 4; j++) rm[j] = fmaxf(rm[j], __shfl_xor(rm[j], off));
      t2v += rm[0] + rm[1] + rm[2] + rm[3];
    }
    t2v += __shfl_xor(t2v, 16);
    t2v += __shfl_xor(t2v, 32);

    float v2t = 0.f;
#pragma unroll
    for (int ni = 0; ni < 4; ni++) {
      float cm = -INFINITY;
#pragma unroll
      for (int mi = ph * 4; mi < ph * 4 + 4; mi++)
#pragma unroll
        for (int j = 0; j < 4; j++) cm = fmaxf(cm, acc[mi][ni][j]);
      cm = fmaxf(cm, __shfl_xor(cm, 16));
      cm = fmaxf(cm, __shfl_xor(cm, 32));
      v2t += cm;
    }
#pragma unroll
    for (int off = 1; off < 16; off <<= 1) v2t += __shfl_xor(v2t, off);

    const int a = by * 4 + wr * 2 + ph, b = bx * 4 + wc;
    float r = lsv * 0.5f * (t2v / am2[ph] + v2t / 64.0f);
    if (lane == 0) {
      out[a * NB + b] = r;                 // r
      out[NB * NB + b * NB + a] = r;       // r.T
    }
  }
}

// ---------------------------------------------------------------------------
extern "C" void kernel_launch(void* const* d_in, const int* in_sizes, int n_in,
                              void* d_out, int out_size, void* d_ws, size_t ws_size,
                              hipStream_t stream) {
  const float* query = (const float*)d_in[0];
  const float* key   = (const float*)d_in[1];
  const float* amask = (const float*)d_in[2];
  const float* Wq    = (const float*)d_in[3];
  const float* bq    = (const float*)d_in[4];
  const float* Wk    = (const float*)d_in[5];
  const float* bk    = (const float*)d_in[6];
  const float* ls    = (const float*)d_in[7];

  char* ws = (char*)d_ws;
  ushort_t* Qb = (ushort_t*)(ws);                      // 8 MB
  ushort_t* Kb = (ushort_t*)(ws + 8 * 1024 * 1024);    // 8 MB

  proj_kernel<<<dim3(4, 64, 2), 256, 0, stream>>>(query, Wq, bq, Qb, key, Wk, bk, Kb);
  pairs_kernel<<<dim3(1024), 512, 0, stream>>>(Qb, Kb, amask, ls, (float*)d_out);
}